// Round 9
// baseline (239.351 us; speedup 1.0000x reference)
//
#include <hip/hip_runtime.h>

#define TSTEPS 512
#define BPB    4                  // batches per block, rows {0,4,8,12}
#define ROWB   256                // bytes per A row (hf slots 0..63 used)
#define ABYTES (16 * ROWB)        // 4096
#define KSTEPS 2                  // K = 64 (hf only; x+bias via VALU)

typedef short bf16x8 __attribute__((ext_vector_type(8)));
typedef float f32x4  __attribute__((ext_vector_type(4)));

__device__ __forceinline__ float fast_sigmoid(float x) {
    return __builtin_amdgcn_rcpf(1.0f + __expf(-x));
}
__device__ __forceinline__ float fast_tanh(float x) {
    return 1.0f - 2.0f * __builtin_amdgcn_rcpf(__expf(2.0f * x) + 1.0f);
}
__device__ __forceinline__ unsigned int f2bf(float f) {   // RTN-even
    unsigned int u = __builtin_bit_cast(unsigned int, f);
    return (u + 0x7FFFu + ((u >> 16) & 1u)) >> 16;
}

// gates = hf_prev @ M (bf16 MFMA, K=64) + fp32(W_ih. x_t + bias)  [VALU]
// M = W_hr^T W_hh^T (projection composed away), resident B-fragments.
// Block: 4 waves, 4 batches (A rows {0,4,8,12} = r=0 C rows -> 1 nonlin
// iter, zero masked lanes). grid 512 -> 2 blocks/CU co-scheduled (m114).
// vs round 8: x+bias k-step ejected from MFMA (matrix pipe 465->310
// cyc/SIMD/step), x staged per-64-step chunk in LDS (no per-step global
// load / split_pack), hf stores pair-merged to b32 (kills sub-dword
// write bank conflicts).
__global__ __launch_bounds__(256, 2) void lstm_mfma6_kernel(
    const float* __restrict__ x,      // [B, T, 4]
    const float* __restrict__ W_ih,   // [256, 4]
    const float* __restrict__ W_hh,   // [256, 49]
    const float* __restrict__ b_ih,   // [256]
    const float* __restrict__ b_hh,   // [256]
    const float* __restrict__ W_hr,   // [49, 64]
    const float* __restrict__ W_out,  // [49, 49]
    const float* __restrict__ b_out,  // [49]
    float* __restrict__ out)          // [B, 49]
{
    const int tid = threadIdx.x;
    const int w   = tid >> 6;         // wave 0..3 (also: local batch for refill)
    const int l   = tid & 63;
    const int g4  = l >> 4;           // lane k-group / local batch in main loop
    const int ln  = l & 15;
    const int b0  = blockIdx.x * BPB;

    __shared__ __align__(128) unsigned char Abuf[2 * ABYTES];   // hf dbuf, 8KB
    __shared__ __align__(128) unsigned char Xreg[64 * 64];      // [64 steps][4 batch][4 f32]
    __shared__ __align__(16)  float hf32[BPB][64];
    __shared__ float hproj[BPB][52];

    // ---------------- prologue ----------------
    for (int i = tid; i < (2 * ABYTES) / 4; i += 256)
        ((unsigned int*)Abuf)[i] = 0u;

    // M[k][n] for this lane's 16 k-slots (k = s*32 + g4*8 + j, s=0,1) x 4 n-cols
    float Msum[4][16];
    #pragma unroll
    for (int t4 = 0; t4 < 4; ++t4)
        #pragma unroll
        for (int i = 0; i < 16; ++i) Msum[t4][i] = 0.0f;

    for (int p = 0; p < 49; ++p) {
        float wr[16];
        #pragma unroll
        for (int s = 0; s < 2; ++s)
            #pragma unroll
            for (int j = 0; j < 8; ++j)
                wr[s * 8 + j] = W_hr[p * 64 + s * 32 + g4 * 8 + j];
        #pragma unroll
        for (int t4 = 0; t4 < 4; ++t4) {
            const float whh = W_hh[(t4 * 64 + w * 16 + ln) * 49 + p];
            #pragma unroll
            for (int i = 0; i < 16; ++i) Msum[t4][i] += whh * wr[i];
        }
    }

    // Resident B fragments (K=64 only): Bf[gate][kstep]
    bf16x8 Bf[4][KSTEPS];
    union U { unsigned int d[4]; bf16x8 v; };
    #pragma unroll
    for (int t4 = 0; t4 < 4; ++t4) {
        #pragma unroll
        for (int s = 0; s < 2; ++s) {
            U u;
            #pragma unroll
            for (int jj = 0; jj < 4; ++jj) {
                const unsigned int e0 = f2bf(Msum[t4][s * 8 + 2 * jj]);
                const unsigned int e1 = f2bf(Msum[t4][s * 8 + 2 * jj + 1]);
                u.d[jj] = e0 | (e1 << 16);
            }
            Bf[t4][s] = u.v;
        }
    }

    // Per-lane fp32 input weights + bias for this lane's 4 gate columns
    float wih[4][4], bsum[4];
    #pragma unroll
    for (int t4 = 0; t4 < 4; ++t4) {
        const int n = t4 * 64 + w * 16 + ln;
        #pragma unroll
        for (int c = 0; c < 4; ++c) wih[t4][c] = W_ih[n * 4 + c];
        bsum[t4] = b_ih[n] + b_hh[n];
    }

    // Hoisted addresses
    int aoff[KSTEPS];
    #pragma unroll
    for (int s = 0; s < KSTEPS; ++s)
        aoff[s] = (ln * ROWB + s * 64 + g4 * 16) ^ ((ln & 7) << 4);
    const int wrow  = g4 * 4;                       // this lane's C row (r=0)
    const int woffp = (wrow * ROWB + 2 * (w * 16 + ln)) ^ ((wrow & 7) << 4);

    float cst = 0.f;
    float hffin = 0.f;
    int cur = 0;
    __syncthreads();

    // ---------------- recurrence ----------------
    for (int t = 0; t < TSTEPS; ++t) {
        // refill x chunk: wave w stages batch w's next 64 timesteps (f32)
        if ((t & 63) == 0) {
            const float4 xv = *reinterpret_cast<const float4*>(
                x + ((size_t)(b0 + w) * TSTEPS + (t + l)) * 4);
            *reinterpret_cast<float4*>(Xreg + l * 64 + w * 16) = xv;
            __syncthreads();
        }

        const unsigned char* Ab = Abuf + cur * ABYTES;
        const bf16x8 af0 = *(const bf16x8*)(Ab + aoff[0]);
        const bf16x8 af1 = *(const bf16x8*)(Ab + aoff[1]);
        // broadcast x_t for this lane's batch (g4)
        const float4 xt = *reinterpret_cast<const float4*>(
            Xreg + ((t & 63) << 6) + (g4 << 4));

        f32x4 aI = {0.f, 0.f, 0.f, 0.f}, aF = aI, aG = aI, aO = aI;
        aI = __builtin_amdgcn_mfma_f32_16x16x32_bf16(af0, Bf[0][0], aI, 0, 0, 0);
        aF = __builtin_amdgcn_mfma_f32_16x16x32_bf16(af0, Bf[1][0], aF, 0, 0, 0);
        aG = __builtin_amdgcn_mfma_f32_16x16x32_bf16(af0, Bf[2][0], aG, 0, 0, 0);
        aO = __builtin_amdgcn_mfma_f32_16x16x32_bf16(af0, Bf[3][0], aO, 0, 0, 0);
        aI = __builtin_amdgcn_mfma_f32_16x16x32_bf16(af1, Bf[0][1], aI, 0, 0, 0);
        aF = __builtin_amdgcn_mfma_f32_16x16x32_bf16(af1, Bf[1][1], aF, 0, 0, 0);
        aG = __builtin_amdgcn_mfma_f32_16x16x32_bf16(af1, Bf[2][1], aG, 0, 0, 0);
        aO = __builtin_amdgcn_mfma_f32_16x16x32_bf16(af1, Bf[3][1], aO, 0, 0, 0);

        // fp32 input contribution (exact): xg = W_ih . x_t + (b_ih + b_hh)
        const float xgI = fmaf(wih[0][3], xt.w, fmaf(wih[0][2], xt.z,
                          fmaf(wih[0][1], xt.y, fmaf(wih[0][0], xt.x, bsum[0]))));
        const float xgF = fmaf(wih[1][3], xt.w, fmaf(wih[1][2], xt.z,
                          fmaf(wih[1][1], xt.y, fmaf(wih[1][0], xt.x, bsum[1]))));
        const float xgG = fmaf(wih[2][3], xt.w, fmaf(wih[2][2], xt.z,
                          fmaf(wih[2][1], xt.y, fmaf(wih[2][0], xt.x, bsum[2]))));
        const float xgO = fmaf(wih[3][3], xt.w, fmaf(wih[3][2], xt.z,
                          fmaf(wih[3][1], xt.y, fmaf(wih[3][0], xt.x, bsum[3]))));

        unsigned char* An = Abuf + (cur ^ 1) * ABYTES;
        {
            const float gi = fast_sigmoid(aI[0] + xgI);
            const float gf = fast_sigmoid(aF[0] + xgF);
            const float gg = fast_tanh(aG[0] + xgG);
            const float go = fast_sigmoid(aO[0] + xgO);
            cst = gf * cst + gi * gg;
            const float hf = go * fast_tanh(cst);
            hffin = hf;
            // pair-merge to b32: even lane packs (self | partner<<16)
            const unsigned int ub = f2bf(hf);
            const unsigned int up = __shfl_xor(ub, 1);
            if (!(ln & 1))
                *(unsigned int*)(An + woffp) = ub | (up << 16);
        }

        __syncthreads();
        cur ^= 1;
    }

    // ---------------- epilogue (exact fp32 two-stage) ----------------
    hf32[g4][w * 16 + ln] = hffin;
    __syncthreads();

    for (int idx = tid; idx < BPB * 49; idx += 256) {
        const int bb = idx / 49, q = idx - bb * 49;
        float s = 0.0f;
        #pragma unroll 8
        for (int h = 0; h < 64; ++h) s += hf32[bb][h] * W_hr[q * 64 + h];
        hproj[bb][q] = s;
    }
    __syncthreads();
    for (int idx = tid; idx < BPB * 49; idx += 256) {
        const int bb = idx / 49, q2 = idx - bb * 49;
        float s = b_out[q2];
        #pragma unroll 7
        for (int p = 0; p < 49; ++p) s += hproj[bb][p] * W_out[q2 * 49 + p];
        out[(b0 + bb) * 49 + q2] = s;
    }
}

extern "C" void kernel_launch(void* const* d_in, const int* in_sizes, int n_in,
                              void* d_out, int out_size, void* d_ws, size_t ws_size,
                              hipStream_t stream) {
    (void)in_sizes; (void)n_in; (void)d_ws; (void)ws_size; (void)out_size;
    const float* x     = (const float*)d_in[0];
    const float* W_ih  = (const float*)d_in[1];
    const float* W_hh  = (const float*)d_in[2];
    const float* b_ih  = (const float*)d_in[3];
    const float* b_hh  = (const float*)d_in[4];
    const float* W_hr  = (const float*)d_in[5];
    const float* W_out = (const float*)d_in[6];
    const float* b_out = (const float*)d_in[7];
    float* outp = (float*)d_out;

    lstm_mfma6_kernel<<<dim3(2048 / BPB), dim3(256), 0, stream>>>(
        x, W_ih, W_hh, b_ih, b_hh, W_hr, W_out, b_out, outp);
}